// Round 1
// baseline (686.708 us; speedup 1.0000x reference)
//
#include <hip/hip_runtime.h>
#include <hip/hip_bf16.h>

// ExpertODEEnsemble: E=8, D=64, H=512, B=32768.
// R16: two independent 4-wave pipelines per CU.
//   512 blocks x 256 threads (4 waves), 64-row tiles -> LDS ~76KB -> 2 blocks/CU.
//   Wave tile M=128 x N=64 (acc 128 regs, same as before). One block's
//   epilogue/sync bubbles overlap the other block's MFMA bursts.
//   L4 is K-quartered per wave (reads only its OWN act slabs) -> L4 and L1
//   need no flag traffic at all. prep_kernel + ws layout unchanged from R15.

typedef unsigned short ushort_t;
typedef unsigned int u32;
typedef unsigned long long u64;
typedef __attribute__((ext_vector_type(8))) short short8;
typedef __attribute__((ext_vector_type(4))) float floatx4;
typedef __attribute__((ext_vector_type(16))) float floatx16;
typedef __attribute__((ext_vector_type(4))) int intx4;

// ws layout (bytes); granule = 16 B = 8 bf16 along k  (UNCHANGED)
#define W1A_OFF 0u          // per e (65536 B): ow*8192 + kc*2048 + ol*1024 + lane*16
#define W2A_OFF 524288u     // per e (524288B): ow*65536 + kc*2048 + ol*1024 + lane*16
#define W3A_OFF 4718592u
#define W4A_OFF 8912896u    // per e (65536 B): o4*32768 + kc*1024 + lane*16
#define XB_OFF  9437184u    // x row-major bf16 [32768][64]
#define B1E_OFF 13631488u   // b1_eff fp32 [8][512]

// LDS layout (dynamic): act 32 slabs * SLAB; x 4 slabs * SLAB; flags.
// slab = one kc (16 k) x 64 rows: nt*1024 + (khalf*32 + r31)*16, +64B pad.
#define SLAB 2112
#define X_OFF_L 67584       // 32*SLAB
#define SYNC_OFF 76032      // X_OFF_L + 4*SLAB ; kcp[4] then pub[4]
#define SMEM_SZ 76096

static __device__ __forceinline__ u32 pk2bf(float a, float b) {
  union { __hip_bfloat162 h; u32 u; } v;
  v.h = __float22bfloat162_rn(make_float2(a, b));
  return v.u;
}

static __device__ __forceinline__ float pade_tanh(float x) {
  // tanh x = x(945+105x^2+x^4)/(945+420x^2+15x^4); |err|<=1e-4 for |x|<=2
  float x2 = x * x;
  float num = __builtin_fmaf(x2, __builtin_fmaf(x2, 1.0f, 105.0f), 945.0f);
  float den = __builtin_fmaf(x2, __builtin_fmaf(x2, 15.0f, 420.0f), 945.0f);
  return x * num * __builtin_amdgcn_rcpf(den);
}

static __device__ __forceinline__ void ald16(const void* g, void* l) {
  __builtin_amdgcn_global_load_lds((__attribute__((address_space(1))) void*)g,
                                   (__attribute__((address_space(3))) void*)l,
                                   16, 0, 0);
}

static __device__ __forceinline__ floatx16 mfma32(short8 a, short8 b, floatx16 c) {
  return __builtin_amdgcn_mfma_f32_32x32x16_bf16(a, b, c, 0, 0, 0);
}

// spin until *p >= tgt (LDS flag; all lanes read same addr -> broadcast)
static __device__ __forceinline__ void waitge(const int* p, int tgt) {
  while (*(volatile const int*)p < tgt) __builtin_amdgcn_s_sleep(1);
  __asm__ __volatile__("" ::: "memory");
}

// publish: drain own LDS ops, then one lane bumps the counter
static __device__ __forceinline__ void bump(int* p, int lane) {
  __asm__ __volatile__("s_waitcnt lgkmcnt(0)" ::: "memory");
  if (lane == 0) atomicAdd(p, 1);
}

// ------ prep: thread == dest granule (lane-fastest) -> coalesced writes ------
// (byte-identical to R15)
__global__ __launch_bounds__(256) void prep_kernel(
    const float* __restrict__ t, const float* __restrict__ x,
    const float* __restrict__ omega, const float* __restrict__ W1,
    const float* __restrict__ b1, const float* __restrict__ W2,
    const float* __restrict__ W3, const float* __restrict__ W4,
    char* __restrict__ ws) {
  int i = blockIdx.x * 256 + threadIdx.x;
  if (i < 32768) {                       // W1A: d=((w*4+kc)*2+ol)*64+lane
    int e = i >> 12, d = i & 4095;
    int lane = d & 63, q = d >> 6;
    int ol = q & 1, kc = (q >> 1) & 3, w = q >> 3;
    int outr = w * 64 + ol * 32 + (lane & 31);
    int kg = kc * 2 + (lane >> 5);
    const float* s = W1 + (e * 512 + outr) * 67 + kg * 8;   // stride 67: scalar
    ((intx4*)(ws + W1A_OFF))[i] = (intx4){
        (int)pk2bf(s[0], s[1]), (int)pk2bf(s[2], s[3]),
        (int)pk2bf(s[4], s[5]), (int)pk2bf(s[6], s[7])};
    return;
  }
  i -= 32768;
  if (i < 262144) {                      // W2A: d=((w*32+kc)*2+ol)*64+lane
    int e = i >> 15, d = i & 32767;
    int lane = d & 63, q = d >> 6;
    int ol = q & 1, kc = (q >> 1) & 31, w = q >> 6;
    int outr = w * 64 + ol * 32 + (lane & 31);
    int kg = kc * 2 + (lane >> 5);
    const floatx4* s = (const floatx4*)(W2 + ((e << 9) + outr) * 512 + (kg << 3));
    floatx4 lo = s[0], hi = s[1];
    ((intx4*)(ws + W2A_OFF))[i] = (intx4){
        (int)pk2bf(lo[0], lo[1]), (int)pk2bf(lo[2], lo[3]),
        (int)pk2bf(hi[0], hi[1]), (int)pk2bf(hi[2], hi[3])};
    return;
  }
  i -= 262144;
  if (i < 262144) {                      // W3A
    int e = i >> 15, d = i & 32767;
    int lane = d & 63, q = d >> 6;
    int ol = q & 1, kc = (q >> 1) & 31, w = q >> 6;
    int outr = w * 64 + ol * 32 + (lane & 31);
    int kg = kc * 2 + (lane >> 5);
    const floatx4* s = (const floatx4*)(W3 + ((e << 9) + outr) * 512 + (kg << 3));
    floatx4 lo = s[0], hi = s[1];
    ((intx4*)(ws + W3A_OFF))[i] = (intx4){
        (int)pk2bf(lo[0], lo[1]), (int)pk2bf(lo[2], lo[3]),
        (int)pk2bf(hi[0], hi[1]), (int)pk2bf(hi[2], hi[3])};
    return;
  }
  i -= 262144;
  if (i < 32768) {                       // W4A: d=(o4*32+kc)*64+lane
    int e = i >> 12, d = i & 4095;
    int lane = d & 63, q = d >> 6;
    int kc = q & 31, o4 = q >> 5;
    int outr = o4 * 32 + (lane & 31);
    int kg = kc * 2 + (lane >> 5);
    const floatx4* s = (const floatx4*)(W4 + ((e << 6) + outr) * 512 + (kg << 3));
    floatx4 lo = s[0], hi = s[1];
    ((intx4*)(ws + W4A_OFF))[i] = (intx4){
        (int)pk2bf(lo[0], lo[1]), (int)pk2bf(lo[2], lo[3]),
        (int)pk2bf(hi[0], hi[1]), (int)pk2bf(hi[2], hi[3])};
    return;
  }
  i -= 32768;
  if (i < 262144) {                      // x -> bf16 (coalesced both ways)
    const floatx4* s = (const floatx4*)(x + i * 8);
    floatx4 lo = s[0], hi = s[1];
    ((intx4*)(ws + XB_OFF))[i] = (intx4){
        (int)pk2bf(lo[0], lo[1]), (int)pk2bf(lo[2], lo[3]),
        (int)pk2bf(hi[0], hi[1]), (int)pk2bf(hi[2], hi[3])};
    return;
  }
  i -= 262144;
  if (i < 4096) {                        // b1_eff
    float tv = t[0];
    int e = i >> 9;
    float om = omega[e];
    ((float*)(ws + B1E_OFF))[i] = b1[i] + tv * W1[i * 67 + 64]
        + sinf(om * tv) * W1[i * 67 + 65] + cosf(om * tv) * W1[i * 67 + 66];
  }
}

// One MLP layer for the 4-wave block. Wave w: outs [128w, 128w+128) (a0..a3 =
// old-w panels 2w,2w+1 x ol 0,1), rows = all 64 (nt 0,1). Group g = slabs
// 4g..4g+3 (k [64g,64g+64)), produced by wave g>>1.
// BUMP: bump kcp after each consumed group (needed only when a later epi_wait
// depends on it, i.e. L2/L3). do_epi: wait for all waves to have consumed this
// wave's 2 groups of the PREVIOUS layer before overwriting its slabs.
template <int NKC, bool ISX, bool BUMP>
static __device__ __forceinline__ void mlp_layer4(
    const char* __restrict__ bsrc, char* __restrict__ act,
    int* kcp, int* pub, int lane, int w, int q1, int r31,
    const char* __restrict__ Abase, const float* __restrict__ bias,
    int pub_tgt, int epi_base, bool do_epi) {
  const int voff = lane * 16;
  const int AH = NKC * 2048;                 // old-w panel stride
  const char* spA = Abase + (2 * w) * AH + voff;

  floatx16 acc[4][2];
#pragma unroll
  for (int ol = 0; ol < 4; ++ol) {
    int fe0 = w * 128 + ol * 32 + 4 * q1;
#pragma unroll
    for (int g = 0; g < 4; ++g) {
      floatx4 bv = *(const floatx4*)(bias + fe0 + 8 * g);
#pragma unroll
      for (int nt = 0; nt < 2; ++nt) {
        acc[ol][nt][4 * g + 0] = bv[0];
        acc[ol][nt][4 * g + 1] = bv[1];
        acc[ol][nt][4 * g + 2] = bv[2];
        acc[ol][nt][4 * g + 3] = bv[3];
      }
    }
  }
  short8 a0 = *(const short8*)(spA);
  short8 a1 = *(const short8*)(spA + 1024);
  short8 a2 = *(const short8*)(spA + AH);
  short8 a3 = *(const short8*)(spA + AH + 1024);
  spA += 2048;

  const int NG = NKC / 4;
#pragma unroll 1
  for (int g = 0; g < NG; ++g) {
    if (!ISX) waitge(pub + (g >> 1), pub_tgt);
    const char* gb = bsrc + g * (4 * SLAB) + voff;
    short8 b0 = *(const short8*)(gb);
    short8 b1v = *(const short8*)(gb + 1024);
#pragma unroll
    for (int j = 0; j < 4; ++j) {
      short8 an0 = *(const short8*)(spA);             // linear A prefetch; overrun in-ws
      short8 an1 = *(const short8*)(spA + 1024);
      short8 an2 = *(const short8*)(spA + AH);
      short8 an3 = *(const short8*)(spA + AH + 1024);
      spA += 2048;
      const char* bn = gb + ((j + 1) & 3) * SLAB;     // wrap inside group (flag-safe)
      short8 bn0 = *(const short8*)(bn);
      short8 bn1 = *(const short8*)(bn + 1024);
      acc[0][0] = mfma32(a0, b0, acc[0][0]);
      acc[0][1] = mfma32(a0, b1v, acc[0][1]);
      acc[1][0] = mfma32(a1, b0, acc[1][0]);
      acc[1][1] = mfma32(a1, b1v, acc[1][1]);
      acc[2][0] = mfma32(a2, b0, acc[2][0]);
      acc[2][1] = mfma32(a2, b1v, acc[2][1]);
      acc[3][0] = mfma32(a3, b0, acc[3][0]);
      acc[3][1] = mfma32(a3, b1v, acc[3][1]);
      a0 = an0; a1 = an1; a2 = an2; a3 = an3;
      b0 = bn0; b1v = bn1;
    }
    if (BUMP) bump(kcp + w, lane);       // this wave finished reading group g
  }

  // epilogue: wait until no wave still reads my 8 slabs (groups 2w,2w+1 of the
  // previous layer's consumption), then overwrite
  if (do_epi) {
#pragma unroll 1
    for (int w2 = 0; w2 < 4; ++w2) waitge(kcp + w2, epi_base + 2 * w + 2);
  }
#pragma unroll
  for (int ol = 0; ol < 4; ++ol) {
#pragma unroll
    for (int g = 0; g < 4; ++g) {
      int ko = ol * 4 + g;               // k_local quad; slab = 8w + (ko>>1)
      char* base = act + (8 * w + (ko >> 1)) * SLAB
                   + (((ko & 1) * 32 + r31) << 4) + q1 * 8;
#pragma unroll
      for (int nt = 0; nt < 2; ++nt) {
        float v0 = pade_tanh(acc[ol][nt][4 * g + 0]);
        float v1 = pade_tanh(acc[ol][nt][4 * g + 1]);
        float v2 = pade_tanh(acc[ol][nt][4 * g + 2]);
        float v3 = pade_tanh(acc[ol][nt][4 * g + 3]);
        u32 lo = pk2bf(v0, v1), hi = pk2bf(v2, v3);
        *(u64*)(base + nt * 1024) = ((u64)hi << 32) | lo;
      }
    }
  }
  bump(pub + w, lane);                   // slabs published
}

extern "C" __global__ __launch_bounds__(256, 2) void fused_kernel(
    const char* __restrict__ ws, const float* __restrict__ b2,
    const float* __restrict__ b3, const float* __restrict__ b4,
    const float* __restrict__ ew, float* __restrict__ out) {
  extern __shared__ char smem[];
  char* act = smem;
  char* xreg = smem + X_OFF_L;
  int* kcp = (int*)(smem + SYNC_OFF);
  int* pub = kcp + 4;

  const int t = threadIdx.x, lane = t & 63, w = t >> 6;   // 4 waves
  const int q1 = lane >> 5, r31 = lane & 31;
  const int row0 = blockIdx.x << 6;      // 64-row tile, 512 blocks (2/CU)
  const int voff = lane * 16;

  if (t < 8) ((int*)(smem + SYNC_OFF))[t] = 0;

  // stage x: 8 units of 1KB; unit u: x-slab u>>1, nt u&1
  const ushort_t* xb = (const ushort_t*)(ws + XB_OFF);
#pragma unroll
  for (int s = 0; s < 2; ++s) {
    int u = w + 4 * s, v = u >> 1, nt = u & 1;
    ald16(xb + (row0 + nt * 32 + r31) * 64 + (2 * v + q1) * 8,
          xreg + v * SLAB + nt * 1024);
  }
  __syncthreads();                       // x staged + flags zeroed

  floatx16 oacc[2][2] = {};              // K-quarter partial of D=64 x 64 rows

  for (int e = 0; e < 8; ++e) {
    // L1: reads x (no pub wait); overwrites own slabs last read by own L4 ->
    // program order, no epi wait, no kcp traffic.
    mlp_layer4<4, true, false>(xreg, act, kcp, pub, lane, w, q1, r31,
                               ws + W1A_OFF + e * 65536,
                               (const float*)(ws + B1E_OFF) + e * 512,
                               0, 0, false);
    // L2: consume L1 (pub>=3e+1); epi waits for all waves past groups 2w,2w+1
    mlp_layer4<32, false, true>(act, act, kcp, pub, lane, w, q1, r31,
                                ws + W2A_OFF + e * 524288, b2 + e * 512,
                                3 * e + 1, 16 * e, true);
    // L3
    mlp_layer4<32, false, true>(act, act, kcp, pub, lane, w, q1, r31,
                                ws + W3A_OFF + e * 524288, b3 + e * 512,
                                3 * e + 2, 16 * e + 8, true);

    // L4: M=64 (both o4), N=64 (both nt), K-quarter kc in [8w, 8w+8) ->
    // reads ONLY this wave's own slabs (published by itself): sync-free.
    {
      const char* spA = ws + W4A_OFF + e * 65536 + voff;
      floatx16 acc4[2][2] = {};
      const int kc0 = 8 * w;
      short8 a0 = *(const short8*)(spA + kc0 * 1024);
      short8 a1 = *(const short8*)(spA + (32 + kc0) * 1024);
#pragma unroll 1
      for (int gl = 0; gl < 2; ++gl) {
        int g = 2 * w + gl;
        const char* gb = act + g * (4 * SLAB) + voff;
        short8 b0 = *(const short8*)(gb);
        short8 b1v = *(const short8*)(gb + 1024);
#pragma unroll
        for (int j = 0; j < 4; ++j) {
          int kc = kc0 + gl * 4 + j;
          short8 an0 = *(const short8*)(spA + (kc + 1) * 1024);   // overrun in-ws
          short8 an1 = *(const short8*)(spA + (33 + kc) * 1024);  // overrun in-ws
          const char* bn = gb + ((j + 1) & 3) * SLAB;
          short8 bn0 = *(const short8*)(bn);
          short8 bn1 = *(const short8*)(bn + 1024);
          acc4[0][0] = mfma32(a0, b0, acc4[0][0]);
          acc4[0][1] = mfma32(a0, b1v, acc4[0][1]);
          acc4[1][0] = mfma32(a1, b0, acc4[1][0]);
          acc4[1][1] = mfma32(a1, b1v, acc4[1][1]);
          a0 = an0; a1 = an1; b0 = bn0; b1v = bn1;
        }
      }
#pragma unroll
      for (int nt = 0; nt < 2; ++nt) {
        const float sc = ew[(row0 + nt * 32 + r31) * 8 + e];
        if (w == 0) {                    // bias added exactly once (wave 0)
          const float* bp = b4 + e * 64;
#pragma unroll
          for (int o4 = 0; o4 < 2; ++o4) {
            int fe0 = o4 * 32 + 4 * q1;
#pragma unroll
            for (int g = 0; g < 4; ++g) {
              floatx4 bv = *(const floatx4*)(bp + fe0 + 8 * g);
              oacc[o4][nt][4 * g + 0] += sc * (acc4[o4][nt][4 * g + 0] + bv[0]);
              oacc[o4][nt][4 * g + 1] += sc * (acc4[o4][nt][4 * g + 1] + bv[1]);
              oacc[o4][nt][4 * g + 2] += sc * (acc4[o4][nt][4 * g + 2] + bv[2]);
              oacc[o4][nt][4 * g + 3] += sc * (acc4[o4][nt][4 * g + 3] + bv[3]);
            }
          }
        } else {
#pragma unroll
          for (int o4 = 0; o4 < 2; ++o4)
#pragma unroll
            for (int i = 0; i < 16; ++i)
              oacc[o4][nt][i] += sc * acc4[o4][nt][i];
        }
      }
    }
  }

  // final: merge the 4 K-quarter partials via LDS (act dead), plain stores
  __syncthreads();
#pragma unroll
  for (int o4 = 0; o4 < 2; ++o4)
#pragma unroll
    for (int nt = 0; nt < 2; ++nt)
#pragma unroll
      for (int g = 0; g < 4; ++g) {
        floatx4 p = {oacc[o4][nt][4 * g + 0], oacc[o4][nt][4 * g + 1],
                     oacc[o4][nt][4 * g + 2], oacc[o4][nt][4 * g + 3]};
        // float idx in wave-w region: (nt*32+r31)*64 + o4*32 + g*8 + q1*4
        *(floatx4*)(act + (w * 4096 + (nt * 32 + r31) * 64
                           + o4 * 32 + g * 8 + q1 * 4) * 4) = p;
      }
  __syncthreads();
  {
    float* orow = out + row0 * 64;       // this block's 64x64 fp32 tile
#pragma unroll
    for (int k = 0; k < 4; ++k) {
      int f = w * 1024 + k * 256 + lane * 4;   // float idx in 64x64 tile
      floatx4 s0 = *(const floatx4*)(act + f * 4);
      floatx4 s1 = *(const floatx4*)(act + (4096 + f) * 4);
      floatx4 s2 = *(const floatx4*)(act + (8192 + f) * 4);
      floatx4 s3 = *(const floatx4*)(act + (12288 + f) * 4);
      floatx4 v = {s0[0] + s1[0] + s2[0] + s3[0], s0[1] + s1[1] + s2[1] + s3[1],
                   s0[2] + s1[2] + s2[2] + s3[2], s0[3] + s1[3] + s2[3] + s3[3]};
      *(floatx4*)(orow + f) = v;
    }
  }
}

extern "C" void kernel_launch(void* const* d_in, const int* in_sizes, int n_in,
                              void* d_out, int out_size, void* d_ws, size_t ws_size,
                              hipStream_t stream) {
  const float* t  = (const float*)d_in[0];
  const float* x  = (const float*)d_in[1];
  const float* ew = (const float*)d_in[2];
  const float* om = (const float*)d_in[3];
  const float* W1 = (const float*)d_in[4];
  const float* b1 = (const float*)d_in[5];
  const float* W2 = (const float*)d_in[6];
  const float* b2 = (const float*)d_in[7];
  const float* W3 = (const float*)d_in[8];
  const float* b3 = (const float*)d_in[9];
  const float* W4 = (const float*)d_in[10];
  const float* b4 = (const float*)d_in[11];
  char* ws = (char*)d_ws;
  float* out = (float*)d_out;
  (void)in_sizes; (void)n_in; (void)ws_size; (void)out_size;

  static int smem_set = 0;
  if (!smem_set) {
    hipFuncSetAttribute((const void*)fused_kernel,
                        hipFuncAttributeMaxDynamicSharedMemorySize, SMEM_SZ);
    smem_set = 1;
  }
  // no memset: fused_kernel writes every element of out with plain stores
  prep_kernel<<<3344, 256, 0, stream>>>(t, x, om, W1, b1, W2, W3, W4, ws);
  fused_kernel<<<512, 256, SMEM_SZ, stream>>>(ws, b2, b3, b4, ew, out);
}

// Round 2
// 518.492 us; speedup vs baseline: 1.3244x; 1.3244x over previous
//
#include <hip/hip_runtime.h>
#include <hip/hip_bf16.h>

// ExpertODEEnsemble: E=8, D=64, H=512, B=32768.
// R17: twin 4-wave teams in ONE 512-thread block (1 block/CU).
//   Team T handles rows [128*blk + 64T, +64). Waves w,w+4 share a SIMD ->
//   one wave of each team per SIMD; teams are sync-independent so epilogue/
//   wait phases of one overlap MFMA of the other. Both teams read identical
//   weight streams (L1/L2 dedupe). Register budget <=256/wave (the R16
//   failure was 320/wave -> 1 wave/SIMD):
//     acc 128 (AGPR) + oacc 16 + ~90 arch.
//   - L4: each wave computes a disjoint 32x32 out piece, full K -> oacc=16,
//     no final merge.
//   - W1A/W2A/W3A repacked: the 4 A-frags of a wave per k-step are contiguous
//     (single stream, imm offsets 0/1024/2048/3072).
//   - No B (LDS) prefetch: latency hides under the MFMA backlog.

typedef unsigned short ushort_t;
typedef unsigned int u32;
typedef unsigned long long u64;
typedef __attribute__((ext_vector_type(8))) short short8;
typedef __attribute__((ext_vector_type(4))) float floatx4;
typedef __attribute__((ext_vector_type(16))) float floatx16;
typedef __attribute__((ext_vector_type(4))) int intx4;

// ws layout (bytes); granule = 16 B = 8 bf16 along k
// W1A per e (65536 B):  w4*16384 + kc*4096 + f*1024 + lane*16   (kc<4)
// W2A per e (524288 B): w4*131072 + kc*4096 + f*1024 + lane*16  (kc<32)
// W4A per e (65536 B):  (o4*32 + kc)*1024 + lane*16             (unchanged)
#define W1A_OFF 0u
#define W2A_OFF 524288u
#define W3A_OFF 4718592u
#define W4A_OFF 8912896u
#define XB_OFF  9437184u    // x row-major bf16 [32768][64]
#define B1E_OFF 13631488u   // b1_eff fp32 [8][512]

// LDS: per team: act 32 slabs * SLAB + x 4 slabs * SLAB; then flags.
// slab = one kc (16 k) x 64 rows: nt*1024 + (k16half*32 + r31)*16, +64B pad.
#define SLAB 2112
#define TEAM_SZ 76032       // 36*SLAB
#define SYNC_OFF 152064     // kcp[8] then pub[8]
#define SMEM_SZ 152128

static __device__ __forceinline__ u32 pk2bf(float a, float b) {
  union { __hip_bfloat162 h; u32 u; } v;
  v.h = __float22bfloat162_rn(make_float2(a, b));
  return v.u;
}

static __device__ __forceinline__ float pade_tanh(float x) {
  // tanh x = x(945+105x^2+x^4)/(945+420x^2+15x^4); |err|<=1e-4 for |x|<=2
  float x2 = x * x;
  float num = __builtin_fmaf(x2, __builtin_fmaf(x2, 1.0f, 105.0f), 945.0f);
  float den = __builtin_fmaf(x2, __builtin_fmaf(x2, 15.0f, 420.0f), 945.0f);
  return x * num * __builtin_amdgcn_rcpf(den);
}

static __device__ __forceinline__ void ald16(const void* g, void* l) {
  __builtin_amdgcn_global_load_lds((__attribute__((address_space(1))) void*)g,
                                   (__attribute__((address_space(3))) void*)l,
                                   16, 0, 0);
}

static __device__ __forceinline__ floatx16 mfma32(short8 a, short8 b, floatx16 c) {
  return __builtin_amdgcn_mfma_f32_32x32x16_bf16(a, b, c, 0, 0, 0);
}

// spin until *p >= tgt (LDS flag; all lanes read same addr -> broadcast)
static __device__ __forceinline__ void waitge(const int* p, int tgt) {
  while (*(volatile const int*)p < tgt) __builtin_amdgcn_s_sleep(1);
  __asm__ __volatile__("" ::: "memory");
}

// publish: drain own LDS ops, then one lane bumps the counter
static __device__ __forceinline__ void bump(int* p, int lane) {
  __asm__ __volatile__("s_waitcnt lgkmcnt(0)" ::: "memory");
  if (lane == 0) atomicAdd(p, 1);
}

// ------ prep: thread == dest granule (lane-fastest) -> coalesced writes ------
__global__ __launch_bounds__(256) void prep_kernel(
    const float* __restrict__ t, const float* __restrict__ x,
    const float* __restrict__ omega, const float* __restrict__ W1,
    const float* __restrict__ b1, const float* __restrict__ W2,
    const float* __restrict__ W3, const float* __restrict__ W4,
    char* __restrict__ ws) {
  int i = blockIdx.x * 256 + threadIdx.x;
  if (i < 32768) {                       // W1A: q = w4*16 + kc*4 + f
    int e = i >> 12, d = i & 4095;
    int lane = d & 63, q = d >> 6;
    int f = q & 3, kc = (q >> 2) & 3, w4 = q >> 4;
    int feat = w4 * 128 + f * 32 + (lane & 31);
    int kg = kc * 2 + (lane >> 5);
    const float* s = W1 + (e * 512 + feat) * 67 + kg * 8;   // stride 67: scalar
    ((intx4*)(ws + W1A_OFF))[i] = (intx4){
        (int)pk2bf(s[0], s[1]), (int)pk2bf(s[2], s[3]),
        (int)pk2bf(s[4], s[5]), (int)pk2bf(s[6], s[7])};
    return;
  }
  i -= 32768;
  if (i < 262144) {                      // W2A: q = w4*128 + kc*4 + f
    int e = i >> 15, d = i & 32767;
    int lane = d & 63, q = d >> 6;
    int f = q & 3, kc = (q >> 2) & 31, w4 = q >> 7;
    int feat = w4 * 128 + f * 32 + (lane & 31);
    int kg = kc * 2 + (lane >> 5);
    const floatx4* s = (const floatx4*)(W2 + ((e << 9) + feat) * 512 + (kg << 3));
    floatx4 lo = s[0], hi = s[1];
    ((intx4*)(ws + W2A_OFF))[i] = (intx4){
        (int)pk2bf(lo[0], lo[1]), (int)pk2bf(lo[2], lo[3]),
        (int)pk2bf(hi[0], hi[1]), (int)pk2bf(hi[2], hi[3])};
    return;
  }
  i -= 262144;
  if (i < 262144) {                      // W3A
    int e = i >> 15, d = i & 32767;
    int lane = d & 63, q = d >> 6;
    int f = q & 3, kc = (q >> 2) & 31, w4 = q >> 7;
    int feat = w4 * 128 + f * 32 + (lane & 31);
    int kg = kc * 2 + (lane >> 5);
    const floatx4* s = (const floatx4*)(W3 + ((e << 9) + feat) * 512 + (kg << 3));
    floatx4 lo = s[0], hi = s[1];
    ((intx4*)(ws + W3A_OFF))[i] = (intx4){
        (int)pk2bf(lo[0], lo[1]), (int)pk2bf(lo[2], lo[3]),
        (int)pk2bf(hi[0], hi[1]), (int)pk2bf(hi[2], hi[3])};
    return;
  }
  i -= 262144;
  if (i < 32768) {                       // W4A: d=(o4*32+kc)*64+lane (unchanged)
    int e = i >> 12, d = i & 4095;
    int lane = d & 63, q = d >> 6;
    int kc = q & 31, o4 = q >> 5;
    int outr = o4 * 32 + (lane & 31);
    int kg = kc * 2 + (lane >> 5);
    const floatx4* s = (const floatx4*)(W4 + ((e << 6) + outr) * 512 + (kg << 3));
    floatx4 lo = s[0], hi = s[1];
    ((intx4*)(ws + W4A_OFF))[i] = (intx4){
        (int)pk2bf(lo[0], lo[1]), (int)pk2bf(lo[2], lo[3]),
        (int)pk2bf(hi[0], hi[1]), (int)pk2bf(hi[2], hi[3])};
    return;
  }
  i -= 32768;
  if (i < 262144) {                      // x -> bf16 (coalesced both ways)
    const floatx4* s = (const floatx4*)(x + i * 8);
    floatx4 lo = s[0], hi = s[1];
    ((intx4*)(ws + XB_OFF))[i] = (intx4){
        (int)pk2bf(lo[0], lo[1]), (int)pk2bf(lo[2], lo[3]),
        (int)pk2bf(hi[0], hi[1]), (int)pk2bf(hi[2], hi[3])};
    return;
  }
  i -= 262144;
  if (i < 4096) {                        // b1_eff
    float tv = t[0];
    int e = i >> 9;
    float om = omega[e];
    ((float*)(ws + B1E_OFF))[i] = b1[i] + tv * W1[i * 67 + 64]
        + sinf(om * tv) * W1[i * 67 + 65] + cosf(om * tv) * W1[i * 67 + 66];
  }
}

// One MLP layer for a 4-wave team. Wave w4: feats [128*w4, +128) (4 frags,
// contiguous in ws), rows = all 64 (nt 0,1). Group g = slabs 4g..4g+3
// (k [64g, 64g+64)), produced by team wave g>>1.
// kcp counts consumed groups (L2:8 + L3:8 + L4:8 = 24/expert); pub counts
// published layers (3/expert). do_epi: before overwriting own 8 slabs, wait
// until every team wave consumed my groups 2w4, 2w4+1 of the previous layer.
template <int NKC, bool ISX, bool BUMP>
static __device__ __forceinline__ void mlp_layer_t(
    const char* __restrict__ bsrc, char* __restrict__ act,
    int* kcp, int* pub, int lane, int w4, int q1, int r31,
    const char* __restrict__ Abase, const float* __restrict__ bias,
    int pub_tgt, int epi_base, bool do_epi) {
  const int voff = lane * 16;
  const char* spA = Abase + w4 * (NKC * 4096) + voff;

  floatx16 acc[4][2];
#pragma unroll
  for (int f = 0; f < 4; ++f) {
    int fe0 = w4 * 128 + f * 32 + 4 * q1;
#pragma unroll
    for (int g = 0; g < 4; ++g) {
      floatx4 bv = *(const floatx4*)(bias + fe0 + 8 * g);
#pragma unroll
      for (int nt = 0; nt < 2; ++nt) {
        acc[f][nt][4 * g + 0] = bv[0];
        acc[f][nt][4 * g + 1] = bv[1];
        acc[f][nt][4 * g + 2] = bv[2];
        acc[f][nt][4 * g + 3] = bv[3];
      }
    }
  }
  short8 a0 = *(const short8*)(spA);
  short8 a1 = *(const short8*)(spA + 1024);
  short8 a2 = *(const short8*)(spA + 2048);
  short8 a3 = *(const short8*)(spA + 3072);
  spA += 4096;

  const int NG = NKC / 4;
#pragma unroll 1
  for (int g = 0; g < NG; ++g) {
    if (!ISX) waitge(pub + (g >> 1), pub_tgt);
    const char* gb = bsrc + g * (4 * SLAB) + voff;
#pragma unroll
    for (int j = 0; j < 4; ++j) {
      const char* sb = gb + j * SLAB;
      short8 b0 = *(const short8*)(sb);
      short8 b1v = *(const short8*)(sb + 1024);
      short8 an0 = *(const short8*)(spA);          // linear A prefetch; overrun in-ws
      short8 an1 = *(const short8*)(spA + 1024);
      short8 an2 = *(const short8*)(spA + 2048);
      short8 an3 = *(const short8*)(spA + 3072);
      spA += 4096;
      acc[0][0] = mfma32(a0, b0, acc[0][0]);
      acc[0][1] = mfma32(a0, b1v, acc[0][1]);
      acc[1][0] = mfma32(a1, b0, acc[1][0]);
      acc[1][1] = mfma32(a1, b1v, acc[1][1]);
      acc[2][0] = mfma32(a2, b0, acc[2][0]);
      acc[2][1] = mfma32(a2, b1v, acc[2][1]);
      acc[3][0] = mfma32(a3, b0, acc[3][0]);
      acc[3][1] = mfma32(a3, b1v, acc[3][1]);
      a0 = an0; a1 = an1; a2 = an2; a3 = an3;
    }
    if (BUMP) bump(kcp + w4, lane);      // this wave finished reading group g
  }

  if (do_epi) {
#pragma unroll 1
    for (int w2 = 0; w2 < 4; ++w2) waitge(kcp + w2, epi_base + 2 * w4 + 2);
  }
#pragma unroll
  for (int f = 0; f < 4; ++f) {
#pragma unroll
    for (int g = 0; g < 4; ++g) {
      int ko = f * 4 + g;                // slab = 8*w4 + (ko>>1), k16half = ko&1
      char* base = act + (8 * w4 + (ko >> 1)) * SLAB
                   + (((ko & 1) * 32 + r31) << 4) + q1 * 8;
#pragma unroll
      for (int nt = 0; nt < 2; ++nt) {
        float v0 = pade_tanh(acc[f][nt][4 * g + 0]);
        float v1 = pade_tanh(acc[f][nt][4 * g + 1]);
        float v2 = pade_tanh(acc[f][nt][4 * g + 2]);
        float v3 = pade_tanh(acc[f][nt][4 * g + 3]);
        u32 lo = pk2bf(v0, v1), hi = pk2bf(v2, v3);
        *(u64*)(base + nt * 1024) = ((u64)hi << 32) | lo;
      }
    }
  }
  bump(pub + w4, lane);                  // slabs published
}

extern "C" __global__ __launch_bounds__(512, 2) void fused_kernel(
    const char* __restrict__ ws, const float* __restrict__ b2,
    const float* __restrict__ b3, const float* __restrict__ b4,
    const float* __restrict__ ew, float* __restrict__ out) {
  extern __shared__ char smem[];
  const int t = threadIdx.x, lane = t & 63, w = t >> 6;   // 8 waves
  const int T = w >> 2, w4 = w & 3;      // team, wave-in-team
  const int q1 = lane >> 5, r31 = lane & 31;
  const int voff = lane * 16;
  const int rowT = (blockIdx.x << 7) + T * 64;   // team's 64-row tile

  char* actT = smem + T * TEAM_SZ;
  char* xregT = actT + 32 * SLAB;
  int* kcpT = (int*)(smem + SYNC_OFF) + T * 4;
  int* pubT = (int*)(smem + SYNC_OFF) + 8 + T * 4;

  if (t < 16) ((int*)(smem + SYNC_OFF))[t] = 0;

  // stage x (per team): 8 units of 1KB; unit u: x-slab u>>1, nt u&1
  const ushort_t* xb = (const ushort_t*)(ws + XB_OFF);
#pragma unroll
  for (int s = 0; s < 2; ++s) {
    int u = w4 + 4 * s, v = u >> 1, nt = u & 1;
    ald16(xb + (rowT + nt * 32 + r31) * 64 + (2 * v + q1) * 8,
          xregT + v * SLAB + nt * 1024);
  }
  __syncthreads();                       // x staged + flags zeroed (teams co-start)

  const int o4 = w4 & 1, ntq = w4 >> 1;  // L4: out-half, row-half (disjoint piece)
  floatx16 oacc = {};                    // 32 feats x 32 rows, full K

  for (int e = 0; e < 8; ++e) {
    // L1: reads xreg (never overwritten; no pub wait); epi vs prev expert's L4
    mlp_layer_t<4, true, false>(xregT, actT, kcpT, pubT, lane, w4, q1, r31,
                                ws + W1A_OFF + e * 65536,
                                (const float*)(ws + B1E_OFF) + e * 512,
                                0, 24 * e - 8, e > 0);
    // L2: consume L1 (pub>=3e+1); epi vs this layer's readers of my slabs
    mlp_layer_t<32, false, true>(actT, actT, kcpT, pubT, lane, w4, q1, r31,
                                 ws + W2A_OFF + e * 524288, b2 + e * 512,
                                 3 * e + 1, 24 * e, true);
    // L3
    mlp_layer_t<32, false, true>(actT, actT, kcpT, pubT, lane, w4, q1, r31,
                                 ws + W3A_OFF + e * 524288, b3 + e * 512,
                                 3 * e + 2, 24 * e + 8, true);

    // L4: wave's disjoint 32x32 piece (o4, ntq), full K=512; bumps kcp so
    // next expert's L1 knows when slabs are free.
    {
      const char* spA = ws + W4A_OFF + e * 65536 + o4 * 32768 + voff;
      const float sc = ew[(rowT + ntq * 32 + r31) * 8 + e];
      floatx16 acc4 = {};
      short8 a0 = *(const short8*)(spA);
      short8 a1 = *(const short8*)(spA + 1024);
      short8 a2 = *(const short8*)(spA + 2048);
      short8 a3 = *(const short8*)(spA + 3072);
      spA += 4096;
#pragma unroll 1
      for (int g = 0; g < 8; ++g) {
        short8 an0 = *(const short8*)(spA);        // next group; overrun in-ws
        short8 an1 = *(const short8*)(spA + 1024);
        short8 an2 = *(const short8*)(spA + 2048);
        short8 an3 = *(const short8*)(spA + 3072);
        spA += 4096;
        waitge(pubT + (g >> 1), 3 * e + 3);
        const char* gb = actT + g * (4 * SLAB) + ntq * 1024 + voff;
        short8 b0 = *(const short8*)(gb);
        short8 b1v = *(const short8*)(gb + SLAB);
        short8 b2v = *(const short8*)(gb + 2 * SLAB);
        short8 b3v = *(const short8*)(gb + 3 * SLAB);
        acc4 = mfma32(a0, b0, acc4);
        acc4 = mfma32(a1, b1v, acc4);
        acc4 = mfma32(a2, b2v, acc4);
        acc4 = mfma32(a3, b3v, acc4);
        a0 = an0; a1 = an1; a2 = an2; a3 = an3;
        bump(kcpT + w4, lane);
      }
      const float* bp = b4 + e * 64 + o4 * 32;
#pragma unroll
      for (int gq = 0; gq < 4; ++gq) {
        floatx4 bv = *(const floatx4*)(bp + 8 * gq + 4 * q1);
        oacc[4 * gq + 0] += sc * (acc4[4 * gq + 0] + bv[0]);
        oacc[4 * gq + 1] += sc * (acc4[4 * gq + 1] + bv[1]);
        oacc[4 * gq + 2] += sc * (acc4[4 * gq + 2] + bv[2]);
        oacc[4 * gq + 3] += sc * (acc4[4 * gq + 3] + bv[3]);
      }
    }
  }

  // final: each wave stores its disjoint 32x32 piece; no merge, no barrier
  {
    float* orow = out + (rowT + ntq * 32 + r31) * 64 + o4 * 32;
#pragma unroll
    for (int gq = 0; gq < 4; ++gq) {
      floatx4 v = {oacc[4 * gq + 0], oacc[4 * gq + 1],
                   oacc[4 * gq + 2], oacc[4 * gq + 3]};
      *(floatx4*)(orow + 8 * gq + 4 * q1) = v;
    }
  }
}

extern "C" void kernel_launch(void* const* d_in, const int* in_sizes, int n_in,
                              void* d_out, int out_size, void* d_ws, size_t ws_size,
                              hipStream_t stream) {
  const float* t  = (const float*)d_in[0];
  const float* x  = (const float*)d_in[1];
  const float* ew = (const float*)d_in[2];
  const float* om = (const float*)d_in[3];
  const float* W1 = (const float*)d_in[4];
  const float* b1 = (const float*)d_in[5];
  const float* W2 = (const float*)d_in[6];
  const float* b2 = (const float*)d_in[7];
  const float* W3 = (const float*)d_in[8];
  const float* b3 = (const float*)d_in[9];
  const float* W4 = (const float*)d_in[10];
  const float* b4 = (const float*)d_in[11];
  char* ws = (char*)d_ws;
  float* out = (float*)d_out;
  (void)in_sizes; (void)n_in; (void)ws_size; (void)out_size;

  static int smem_set = 0;
  if (!smem_set) {
    hipFuncSetAttribute((const void*)fused_kernel,
                        hipFuncAttributeMaxDynamicSharedMemorySize, SMEM_SZ);
    smem_set = 1;
  }
  // no memset: fused_kernel writes every element of out with plain stores
  // dest-granule threads: 32768+262144+262144+32768+262144+4096 = 856064
  prep_kernel<<<3344, 256, 0, stream>>>(t, x, om, W1, b1, W2, W3, W4, ws);
  fused_kernel<<<256, 512, SMEM_SZ, stream>>>(ws, b2, b3, b4, ew, out);
}

// Round 3
// 423.230 us; speedup vs baseline: 1.6225x; 1.2251x over previous
//
#include <hip/hip_runtime.h>
#include <hip/hip_bf16.h>

// ExpertODEEnsemble: E=8, D=64, H=512, B=32768.
// R18 = R15 (best, 377us) + three bubble fixes, sync conditions unchanged:
//   1. cross-group B pipeline: j=3 prefetches the NEXT group's 4 slabs
//      (after hoisted waitge) instead of a discarded same-group wrap; group
//      tops no longer cold-load B or re-wait.
//   2. kcp bumps are drainless (bump_sig): MFMA issue already guarantees the
//      protected ds_reads completed; sched_barrier(0) pins the atomic after
//      the MFMAs. pub bumps keep the lgkmcnt(0) drain (they cover ds_writes).
//   3. s_setprio(1/0) around MFMA clusters (T5: producer-epilogue vs
//      consumer-MFMA role diversity exists here).
// R16/R17 lesson (closed): 64-row teams force A4xB2 load ratio -> 2x global
// A-traffic, 30% MfmaUtil. Keep 8-wave/128-row, A2xB4.

typedef unsigned short ushort_t;
typedef unsigned int u32;
typedef unsigned long long u64;
typedef __attribute__((ext_vector_type(8))) short short8;
typedef __attribute__((ext_vector_type(4))) float floatx4;
typedef __attribute__((ext_vector_type(16))) float floatx16;
typedef __attribute__((ext_vector_type(4))) int intx4;

// ws layout (bytes); granule = 16 B = 8 bf16 along k
#define W1A_OFF 0u          // per e (65536 B): granule ((w*4+kc)*2+ol)*64+lane
#define W2A_OFF 524288u     // per e (524288B): granule ((w*32+kc)*2+ol)*64+lane
#define W3A_OFF 4718592u
#define W4A_OFF 8912896u    // per e (65536 B): granule (o4*32+kc)*64+lane
#define XB_OFF  9437184u    // x row-major bf16 [32768][64]
#define B1E_OFF 13631488u   // b1_eff fp32 [8][512]

// LDS layout (dynamic): act 32 slabs * 4224 B; x 4 slabs * 4224; flags.
#define X_OFF_L 135168
#define SYNC_OFF 152064     // kcp[8] then pub[8]
#define SMEM_SZ 152128

static __device__ __forceinline__ u32 pk2bf(float a, float b) {
  union { __hip_bfloat162 h; u32 u; } v;
  v.h = __float22bfloat162_rn(make_float2(a, b));
  return v.u;
}

static __device__ __forceinline__ float pade_tanh(float x) {
  // tanh x = x(945+105x^2+x^4)/(945+420x^2+15x^4); |err|<=1e-4 for |x|<=2
  float x2 = x * x;
  float num = __builtin_fmaf(x2, __builtin_fmaf(x2, 1.0f, 105.0f), 945.0f);
  float den = __builtin_fmaf(x2, __builtin_fmaf(x2, 15.0f, 420.0f), 945.0f);
  return x * num * __builtin_amdgcn_rcpf(den);
}

static __device__ __forceinline__ void ald16(const void* g, void* l) {
  __builtin_amdgcn_global_load_lds((__attribute__((address_space(1))) void*)g,
                                   (__attribute__((address_space(3))) void*)l,
                                   16, 0, 0);
}

static __device__ __forceinline__ floatx16 mfma32(short8 a, short8 b, floatx16 c) {
  return __builtin_amdgcn_mfma_f32_32x32x16_bf16(a, b, c, 0, 0, 0);
}

// spin until *p >= tgt (LDS flag; all lanes read same addr -> broadcast)
static __device__ __forceinline__ void waitge(const int* p, int tgt) {
  while (*(volatile const int*)p < tgt) __builtin_amdgcn_s_sleep(1);
  __asm__ __volatile__("" ::: "memory");
}

// publish after ds_writes: drain own LDS ops, then one lane bumps
static __device__ __forceinline__ void bump(int* p, int lane) {
  __asm__ __volatile__("s_waitcnt lgkmcnt(0)" ::: "memory");
  if (lane == 0) atomicAdd(p, 1);
}

// signal "group reads done": MFMA issue already forced the protected ds_reads
// to complete (HW RAW waitcnt); sched_barrier pins the atomic after the MFMAs.
static __device__ __forceinline__ void bump_sig(int* p, int lane) {
  __builtin_amdgcn_sched_barrier(0);
  if (lane == 0) atomicAdd(p, 1);
}

// ------ prep: thread == dest granule (lane-fastest) -> coalesced writes ------
__global__ __launch_bounds__(256) void prep_kernel(
    const float* __restrict__ t, const float* __restrict__ x,
    const float* __restrict__ omega, const float* __restrict__ W1,
    const float* __restrict__ b1, const float* __restrict__ W2,
    const float* __restrict__ W3, const float* __restrict__ W4,
    char* __restrict__ ws) {
  int i = blockIdx.x * 256 + threadIdx.x;
  if (i < 32768) {                       // W1A: d=((w*4+kc)*2+ol)*64+lane
    int e = i >> 12, d = i & 4095;
    int lane = d & 63, q = d >> 6;
    int ol = q & 1, kc = (q >> 1) & 3, w = q >> 3;
    int outr = w * 64 + ol * 32 + (lane & 31);
    int kg = kc * 2 + (lane >> 5);
    const float* s = W1 + (e * 512 + outr) * 67 + kg * 8;   // stride 67: scalar
    ((intx4*)(ws + W1A_OFF))[i] = (intx4){
        (int)pk2bf(s[0], s[1]), (int)pk2bf(s[2], s[3]),
        (int)pk2bf(s[4], s[5]), (int)pk2bf(s[6], s[7])};
    return;
  }
  i -= 32768;
  if (i < 262144) {                      // W2A: d=((w*32+kc)*2+ol)*64+lane
    int e = i >> 15, d = i & 32767;
    int lane = d & 63, q = d >> 6;
    int ol = q & 1, kc = (q >> 1) & 31, w = q >> 6;
    int outr = w * 64 + ol * 32 + (lane & 31);
    int kg = kc * 2 + (lane >> 5);
    const floatx4* s = (const floatx4*)(W2 + ((e << 9) + outr) * 512 + (kg << 3));
    floatx4 lo = s[0], hi = s[1];
    ((intx4*)(ws + W2A_OFF))[i] = (intx4){
        (int)pk2bf(lo[0], lo[1]), (int)pk2bf(lo[2], lo[3]),
        (int)pk2bf(hi[0], hi[1]), (int)pk2bf(hi[2], hi[3])};
    return;
  }
  i -= 262144;
  if (i < 262144) {                      // W3A
    int e = i >> 15, d = i & 32767;
    int lane = d & 63, q = d >> 6;
    int ol = q & 1, kc = (q >> 1) & 31, w = q >> 6;
    int outr = w * 64 + ol * 32 + (lane & 31);
    int kg = kc * 2 + (lane >> 5);
    const floatx4* s = (const floatx4*)(W3 + ((e << 9) + outr) * 512 + (kg << 3));
    floatx4 lo = s[0], hi = s[1];
    ((intx4*)(ws + W3A_OFF))[i] = (intx4){
        (int)pk2bf(lo[0], lo[1]), (int)pk2bf(lo[2], lo[3]),
        (int)pk2bf(hi[0], hi[1]), (int)pk2bf(hi[2], hi[3])};
    return;
  }
  i -= 262144;
  if (i < 32768) {                       // W4A: d=(o4*32+kc)*64+lane
    int e = i >> 12, d = i & 4095;
    int lane = d & 63, q = d >> 6;
    int kc = q & 31, o4 = q >> 5;
    int outr = o4 * 32 + (lane & 31);
    int kg = kc * 2 + (lane >> 5);
    const floatx4* s = (const floatx4*)(W4 + ((e << 6) + outr) * 512 + (kg << 3));
    floatx4 lo = s[0], hi = s[1];
    ((intx4*)(ws + W4A_OFF))[i] = (intx4){
        (int)pk2bf(lo[0], lo[1]), (int)pk2bf(lo[2], lo[3]),
        (int)pk2bf(hi[0], hi[1]), (int)pk2bf(hi[2], hi[3])};
    return;
  }
  i -= 32768;
  if (i < 262144) {                      // x -> bf16 (coalesced both ways)
    const floatx4* s = (const floatx4*)(x + i * 8);
    floatx4 lo = s[0], hi = s[1];
    ((intx4*)(ws + XB_OFF))[i] = (intx4){
        (int)pk2bf(lo[0], lo[1]), (int)pk2bf(lo[2], lo[3]),
        (int)pk2bf(hi[0], hi[1]), (int)pk2bf(hi[2], hi[3])};
    return;
  }
  i -= 262144;
  if (i < 4096) {                        // b1_eff
    float tv = t[0];
    int e = i >> 9;
    float om = omega[e];
    ((float*)(ws + B1E_OFF))[i] = b1[i] + tv * W1[i * 67 + 64]
        + sinf(om * tv) * W1[i * 67 + 65] + cosf(om * tv) * W1[i * 67 + 66];
  }
}

// act (128 rows): slab kc (stride 4224 B); within: nt*1024 + ((koct&1)*32+r31)*16.

template <int NKC, bool ISX>
static __device__ __forceinline__ void mlp_layer(
    const char* __restrict__ bsrc, char* __restrict__ act,
    int* kcp, int* pub, int lane, int w, int q1, int r31,
    const char* __restrict__ Abase, const float* __restrict__ bias,
    int pub_tgt, int tgt_cov, int tgt_oth, int khm, bool do_epi_wait) {
  const int voff = lane * 16;
  const char* sp = Abase + w * (NKC * 2048) + voff;

  floatx16 acc[2][4];
#pragma unroll
  for (int ol = 0; ol < 2; ++ol) {
    int fe0 = w * 64 + ol * 32 + 4 * q1;
#pragma unroll
    for (int g = 0; g < 4; ++g) {
      floatx4 bv = *(const floatx4*)(bias + fe0 + 8 * g);
#pragma unroll
      for (int nt = 0; nt < 4; ++nt) {
        acc[ol][nt][4 * g + 0] = bv[0];
        acc[ol][nt][4 * g + 1] = bv[1];
        acc[ol][nt][4 * g + 2] = bv[2];
        acc[ol][nt][4 * g + 3] = bv[3];
      }
    }
  }
  short8 a0 = *(const short8*)(sp);
  short8 a1 = *(const short8*)(sp + 1024);
  sp += 2048;

  const int NG = NKC / 4;
  // prologue: wait group 0, warm-load its first slab's 4 nt-chunks
  if (!ISX) waitge(pub + 0, pub_tgt);
  const char* gb = bsrc + voff;
  short8 b0 = *(const short8*)(gb);
  short8 b1v = *(const short8*)(gb + 1024);
  short8 b2 = *(const short8*)(gb + 2048);
  short8 b3 = *(const short8*)(gb + 3072);
#pragma unroll 1
  for (int g = 0; g < NG; ++g) {
#pragma unroll
    for (int j = 0; j < 4; ++j) {
      short8 an0 = *(const short8*)(sp);          // linear A prefetch; overrun in-ws
      short8 an1 = *(const short8*)(sp + 1024);
      sp += 2048;
      short8 bn0 = b0, bn1 = b1v, bn2 = b2, bn3 = b3;
      if (j < 3) {                                // next slab, same group
        const char* bn = gb + (j + 1) * 4224;
        bn0 = *(const short8*)(bn);
        bn1 = *(const short8*)(bn + 1024);
        bn2 = *(const short8*)(bn + 2048);
        bn3 = *(const short8*)(bn + 3072);
      } else if (g + 1 < NG) {                    // cross-group: wait then load
        if (!ISX) waitge(pub + (g + 1), pub_tgt); // steady-state: already set
        gb = bsrc + (g + 1) * (4 * 4224) + voff;
        bn0 = *(const short8*)(gb);
        bn1 = *(const short8*)(gb + 1024);
        bn2 = *(const short8*)(gb + 2048);
        bn3 = *(const short8*)(gb + 3072);
      }
      __builtin_amdgcn_s_setprio(1);
      acc[0][0] = mfma32(a0, b0, acc[0][0]);
      acc[0][1] = mfma32(a0, b1v, acc[0][1]);
      acc[0][2] = mfma32(a0, b2, acc[0][2]);
      acc[0][3] = mfma32(a0, b3, acc[0][3]);
      acc[1][0] = mfma32(a1, b0, acc[1][0]);
      acc[1][1] = mfma32(a1, b1v, acc[1][1]);
      acc[1][2] = mfma32(a1, b2, acc[1][2]);
      acc[1][3] = mfma32(a1, b3, acc[1][3]);
      __builtin_amdgcn_s_setprio(0);
      a0 = an0; a1 = an1;
      b0 = bn0; b1v = bn1; b2 = bn2; b3 = bn3;
    }
    bump_sig(kcp + w, lane);             // this wave finished reading group g
  }

  // epilogue: wait until no wave still reads my act slabs, then overwrite
  if (do_epi_wait) {
    for (int w2 = 0; w2 < 8; ++w2)
      waitge(kcp + w2, ((w2 >> 2) == khm) ? tgt_cov : tgt_oth);
  }
#pragma unroll
  for (int ol = 0; ol < 2; ++ol) {
#pragma unroll
    for (int g = 0; g < 4; ++g) {
      int ko = ol * 4 + g;               // global koct = 8w + ko
      char* base = act + (4 * w + (ko >> 1)) * 4224
                   + (((ko & 1) * 32 + r31) << 4) + q1 * 8;
#pragma unroll
      for (int nt = 0; nt < 4; ++nt) {
        float v0 = pade_tanh(acc[ol][nt][4 * g + 0]);
        float v1 = pade_tanh(acc[ol][nt][4 * g + 1]);
        float v2 = pade_tanh(acc[ol][nt][4 * g + 2]);
        float v3 = pade_tanh(acc[ol][nt][4 * g + 3]);
        u32 lo = pk2bf(v0, v1), hi = pk2bf(v2, v3);
        *(u64*)(base + nt * 1024) = ((u64)hi << 32) | lo;
      }
    }
  }
  bump(pub + w, lane);                   // slab published (drains ds_writes)
}

extern "C" __global__ __launch_bounds__(512) void fused_kernel(
    const char* __restrict__ ws, const float* __restrict__ b2,
    const float* __restrict__ b3, const float* __restrict__ b4,
    const float* __restrict__ ew, float* __restrict__ out) {
  extern __shared__ char smem[];
  char* act = smem;
  char* xreg = smem + X_OFF_L;
  int* kcp = (int*)(smem + SYNC_OFF);
  int* pub = kcp + 8;

  const int t = threadIdx.x, lane = t & 63, w = t >> 6;   // 8 waves
  const int q1 = lane >> 5, r31 = lane & 31;
  const int row0 = blockIdx.x << 7;      // 128-row tile, 256 blocks (1/CU)
  const int voff = lane * 16;

  if (t < 16) ((int*)(smem + SYNC_OFF))[t] = 0;

  // stage x: 16 units of 1KB; unit u: x-slab u>>2, nt u&3
  const ushort_t* xb = (const ushort_t*)(ws + XB_OFF);
#pragma unroll
  for (int s = 0; s < 2; ++s) {
    int u = w + 8 * s, v = u >> 2, nt = u & 3;
    ald16(xb + (row0 + nt * 32 + r31) * 64 + (2 * v + q1) * 8,
          xreg + v * 4224 + nt * 1024);
  }
  __syncthreads();                       // x staged + flags zeroed

  const int rt = w & 3, kh = w >> 2;     // L4: row-tile, K-half
  const int row_l4 = row0 + rt * 32 + r31;
  floatx16 oacc[2] = {};

  for (int e = 0; e < 8; ++e) {
    // L1: reads x (no pub wait); epi waits vs prev expert's L3/L4 readers
    mlp_layer<4, true>(xreg, act, kcp, pub, lane, w, q1, r31,
                       ws + W1A_OFF + e * 65536,
                       (const float*)(ws + B1E_OFF) + e * 512,
                       0, 21 * e + (w & 3) - 3, 21 * e + w - 11, w >> 2, e > 0);
    // L2
    mlp_layer<32, false>(act, act, kcp, pub, lane, w, q1, r31,
                         ws + W2A_OFF + e * 524288, b2 + e * 512,
                         3 * e + 1, 21 * e + w + 2, 21 * e + w + 2, 0, true);
    // L3
    mlp_layer<32, false>(act, act, kcp, pub, lane, w, q1, r31,
                         ws + W3A_OFF + e * 524288, b3 + e * 512,
                         3 * e + 2, 21 * e + w + 10, 21 * e + w + 10, 0, true);

    // L4: M=64 (both o4 halves), N=32 (rows rt), K-half kh; no act writes
    {
      const char* spA = ws + W4A_OFF + e * 65536 + voff;
      const float sc = ew[row_l4 * 8 + e];
      floatx16 acc4[2] = {};
      int kc0 = kh * 16;
      short8 a0 = *(const short8*)(spA + kc0 * 1024);
      short8 a1 = *(const short8*)(spA + 32768 + kc0 * 1024);
      // prologue: wait first group, warm-load its first slab
      int g0 = kh * 4;
      waitge(pub + g0, 3 * e + 3);
      const char* gb = act + g0 * (4 * 4224) + rt * 1024 + voff;
      short8 b = *(const short8*)(gb);
#pragma unroll 1
      for (int gl = 0; gl < 4; ++gl) {
        int g = g0 + gl;
#pragma unroll
        for (int j = 0; j < 4; ++j) {
          int kc = g * 4 + j;
          short8 an0 = *(const short8*)(spA + (kc + 1) * 1024);           // overrun in-ws
          short8 an1 = *(const short8*)(spA + 32768 + (kc + 1) * 1024);   // overrun in-ws
          short8 bn = b;
          if (j < 3) {
            bn = *(const short8*)(gb + (j + 1) * 4224);
          } else if (gl + 1 < 4) {
            waitge(pub + (g + 1), 3 * e + 3);   // steady-state: already set
            gb = act + (g + 1) * (4 * 4224) + rt * 1024 + voff;
            bn = *(const short8*)(gb);
          }
          __builtin_amdgcn_s_setprio(1);
          acc4[0] = mfma32(a0, b, acc4[0]);
          acc4[1] = mfma32(a1, b, acc4[1]);
          __builtin_amdgcn_s_setprio(0);
          a0 = an0; a1 = an1; b = bn;
        }
        bump_sig(kcp + w, lane);
      }
      if (kh == 0) {
        const float* bp = b4 + e * 64;
#pragma unroll
        for (int ol = 0; ol < 2; ++ol) {
          int fe0 = ol * 32 + 4 * q1;
#pragma unroll
          for (int g = 0; g < 4; ++g) {
            floatx4 bv = *(const floatx4*)(bp + fe0 + 8 * g);
            oacc[ol][4 * g + 0] += sc * (acc4[ol][4 * g + 0] + bv[0]);
            oacc[ol][4 * g + 1] += sc * (acc4[ol][4 * g + 1] + bv[1]);
            oacc[ol][4 * g + 2] += sc * (acc4[ol][4 * g + 2] + bv[2]);
            oacc[ol][4 * g + 3] += sc * (acc4[ol][4 * g + 3] + bv[3]);
          }
        }
      } else {
#pragma unroll
        for (int ol = 0; ol < 2; ++ol)
#pragma unroll
          for (int i = 0; i < 16; ++i) oacc[ol][i] += sc * acc4[ol][i];
      }
    }
  }

  // final: merge K-half partners (w, w+4) via LDS (act dead), plain stores
  __syncthreads();
  if (kh == 1) {
#pragma unroll
    for (int ol = 0; ol < 2; ++ol)
#pragma unroll
      for (int g = 0; g < 4; ++g) {
        floatx4 p = {oacc[ol][4 * g + 0], oacc[ol][4 * g + 1],
                     oacc[ol][4 * g + 2], oacc[ol][4 * g + 3]};
        *(floatx4*)(act + rt * 8192 + ol * 4096 + g * 1024 + lane * 16) = p;
      }
  __syncthreads();
  } else { __syncthreads(); }
  if (kh == 0) {
    float* orow = out + row_l4 * 64;
#pragma unroll
    for (int ol = 0; ol < 2; ++ol)
#pragma unroll
      for (int g = 0; g < 4; ++g) {
        floatx4 p = *(const floatx4*)(act + rt * 8192 + ol * 4096 + g * 1024 + lane * 16);
        floatx4 v = {oacc[ol][4 * g + 0] + p[0], oacc[ol][4 * g + 1] + p[1],
                     oacc[ol][4 * g + 2] + p[2], oacc[ol][4 * g + 3] + p[3]};
        *(floatx4*)(orow + ol * 32 + 8 * g + 4 * q1) = v;
      }
  }
}

extern "C" void kernel_launch(void* const* d_in, const int* in_sizes, int n_in,
                              void* d_out, int out_size, void* d_ws, size_t ws_size,
                              hipStream_t stream) {
  const float* t  = (const float*)d_in[0];
  const float* x  = (const float*)d_in[1];
  const float* ew = (const float*)d_in[2];
  const float* om = (const float*)d_in[3];
  const float* W1 = (const float*)d_in[4];
  const float* b1 = (const float*)d_in[5];
  const float* W2 = (const float*)d_in[6];
  const float* b2 = (const float*)d_in[7];
  const float* W3 = (const float*)d_in[8];
  const float* b3 = (const float*)d_in[9];
  const float* W4 = (const float*)d_in[10];
  const float* b4 = (const float*)d_in[11];
  char* ws = (char*)d_ws;
  float* out = (float*)d_out;
  (void)in_sizes; (void)n_in; (void)ws_size; (void)out_size;

  static int smem_set = 0;
  if (!smem_set) {
    hipFuncSetAttribute((const void*)fused_kernel,
                        hipFuncAttributeMaxDynamicSharedMemorySize, SMEM_SZ);
    smem_set = 1;
  }
  // no memset: fused_kernel writes every element of out with plain stores
  // dest-granule threads: 32768+262144+262144+32768+262144+4096 = 856064
  prep_kernel<<<3344, 256, 0, stream>>>(t, x, om, W1, b1, W2, W3, W4, ws);
  fused_kernel<<<256, 512, SMEM_SZ, stream>>>(ws, b2, b3, b4, ew, out);
}